// Round 24
// baseline (66.147 us; speedup 1.0000x reference)
//
#include <hip/hip_runtime.h>

// CPAMDec — R24: low-LDS main (21 KB -> ~7 blocks/CU, 28 waves) for real
// latency hiding. Half-tile staging into ONE 16 KB buffer (cs&7 remap for the
// second half), PV residual from global fp32 (R13-proven), setprio reverted.
// R19's half1-under-P1a overlap, cvt_pk pack, float4 softmax reads, hoisted
// vf/b-frags, full-line writes all retained.
//   energy[px][kk] = sum_c x_bf[px][c] * wqk_bf[c][kk] (+bqk)
//   out[c][px]     = fs * sum_kk vT_bf[c][kk] * attn_bf[kk][px] + x[c][px]
// xl octet layout (R18-verified), half-resident:
//   elem(c,px) = ((c>>5)&7)*1024 + ((c>>3)&3)*256 + px*8 + (c&7)
// Frag layouts HW-verified R5/R6. ws: wqkf @0 | vtf @256K | bqk @512K

#define N_  8
#define C_  512
#define HW_ 4096
#define K_  32

typedef __attribute__((ext_vector_type(8))) short bf16x8;
typedef __attribute__((ext_vector_type(4))) float f32x4;
typedef __attribute__((ext_vector_type(4))) int i32x4;

__device__ __forceinline__ unsigned short f2b(float f) {
    union { float f; unsigned u; } v; v.f = f;
    unsigned r = v.u + 0x7FFFu + ((v.u >> 16) & 1u);   // RNE
    return (unsigned short)(r >> 16);
}
__device__ __forceinline__ int cvtpk(float a, float b) {   // bf16(a) | bf16(b)<<16, RNE
    int r;
    asm("v_cvt_pk_bf16_f32 %0, %1, %2" : "=v"(r) : "v"(a), "v"(b));
    return r;
}

// wqk frag slot: wqk[kk][c] -> elem ((cs*2+kt)*64 + g*16 + (kk&15))*8 + j
__device__ __forceinline__ int wqk_idx(int kk, int c) {
    return ((((c >> 5) * 2 + (kk >> 4)) * 64 + ((c >> 3) & 3) * 16 + (kk & 15)) << 3) + (c & 7);
}

__global__ __launch_bounds__(256) void prep_kernel(
    const float* __restrict__ y, const float* __restrict__ wq, const float* __restrict__ bq,
    const float* __restrict__ wk, const float* __restrict__ bk,
    const float* __restrict__ wv, const float* __restrict__ bv,
    unsigned short* __restrict__ wqkf, float* __restrict__ bqk, unsigned short* __restrict__ vtf)
{
    const int bid = blockIdx.x;
    const int t = threadIdx.x;

    if (bid < 256) {
        // role A: v rows -> vtf frags. block = (n, ct of 16 c).
        __shared__ float vred[3][4][16][8];              // 6 KB
        const int n   = bid >> 5;
        const int ct  = bid & 31;
        const int cl  = t & 15;
        const int kko = (t >> 4) & 3;
        const int jq4 = t >> 6;
        const int c   = ct * 16 + cl;

        const float* yb  = y  + ((size_t)n * K_ + kko * 8) * C_ + jq4 * 128;
        const float* wvb = wv + (size_t)c * C_ + jq4 * 128;
        float acc[8] = {0,0,0,0,0,0,0,0};
        #pragma unroll 4
        for (int jj = 0; jj < 32; ++jj) {
            float4 w4 = *(const float4*)(wvb + jj * 4);
            #pragma unroll
            for (int u = 0; u < 8; ++u) {
                float4 y4 = *(const float4*)(yb + (size_t)u * C_ + jj * 4);
                acc[u] += y4.x * w4.x + y4.y * w4.y + y4.z * w4.z + y4.w * w4.w;
            }
        }
        if (jq4 > 0) {
            #pragma unroll
            for (int u = 0; u < 8; ++u) vred[jq4 - 1][kko][cl][u] = acc[u];
        }
        __syncthreads();
        if (jq4 == 0) {
            const float bvc = bv[c];
            unsigned short o[8];
            #pragma unroll
            for (int u = 0; u < 8; ++u) {
                float s = acc[u] + vred[0][kko][cl][u] + vred[1][kko][cl][u]
                        + vred[2][kko][cl][u] + bvc;
                o[u] = f2b(s);
            }
            i32x4 pk = { (int)(o[0] | ((unsigned)o[1] << 16)), (int)(o[2] | ((unsigned)o[3] << 16)),
                         (int)(o[4] | ((unsigned)o[5] << 16)), (int)(o[6] | ((unsigned)o[7] << 16)) };
            *(i32x4*)(vtf + (size_t)n * (K_ * C_) + (size_t)((ct * 64 + kko * 16 + cl) * 8)) = pk;
        }
    } else {
        // role B: krow -> bqk, wqk frags. block = (n, kk)
        __shared__ __align__(16) float kp[2][128];
        __shared__ __align__(16) float kr[128];
        const int b = bid - 256;
        const int n = b >> 5, kk = b & 31;
        const int o = t & 127, half = t >> 7;

        const float* yb  = y  + ((size_t)n * K_ + kk) * C_ + half * 256;
        const float* wkb = wk + (size_t)o * C_ + half * 256;
        float a = 0.f;
        #pragma unroll 4
        for (int jq = 0; jq < 64; ++jq) {
            float4 w4 = *(const float4*)(wkb + jq * 4);
            float4 y4 = *(const float4*)(yb + jq * 4);
            a += y4.x * w4.x + y4.y * w4.y + y4.z * w4.z + y4.w * w4.w;
        }
        kp[half][o] = a;
        __syncthreads();
        if (t < 128) kr[t] = kp[0][t] + kp[1][t] + bk[t];
        __syncthreads();
        if (t < 64) {
            float s = kr[t] * bq[t] + kr[t + 64] * bq[t + 64];
            #pragma unroll
            for (int d = 32; d > 0; d >>= 1) s += __shfl_down(s, d);
            if (t == 0) bqk[n * K_ + kk] = s;
        }
        const int c1 = t, c2 = t + 256;
        float s1 = 0.f, s2 = 0.f;
        for (int oq = 0; oq < 32; ++oq) {
            float4 k4 = *(const float4*)(&kr[oq * 4]);
            const float* wq0 = wq + (size_t)(oq * 4) * C_;
            s1 += k4.x * wq0[c1] + k4.y * wq0[C_ + c1] + k4.z * wq0[2*C_ + c1] + k4.w * wq0[3*C_ + c1];
            s2 += k4.x * wq0[c2] + k4.y * wq0[C_ + c2] + k4.z * wq0[2*C_ + c2] + k4.w * wq0[3*C_ + c2];
        }
        unsigned short* wqf_n = wqkf + (size_t)n * (K_ * C_);
        wqf_n[wqk_idx(kk, c1)] = f2b(s1);
        wqf_n[wqk_idx(kk, c2)] = f2b(s2);
    }
}

__global__ __launch_bounds__(256) void main_kernel(
    const float* __restrict__ x, const unsigned short* __restrict__ wqkf,
    const unsigned short* __restrict__ vtf, const float* __restrict__ bqk,
    const float* __restrict__ scale, float* __restrict__ out)
{
    __shared__ __align__(16) unsigned short xl[8192];    // 16 KB half-tile buffer
    __shared__ float e_lds[32][36];                       // 4.6 KB -> ~21 KB total

    // XCD swizzle: 128 consecutive tiles (= one image n) per XCD
    const int bid = (blockIdx.x & 7) * 128 + (blockIdx.x >> 3);
    const int n  = bid >> 7;
    const int p0 = (bid & 127) * 32;
    const int t  = threadIdx.x;
    const int w  = t >> 6, l = t & 63;
    const int l15 = l & 15, lg = l >> 4;
    const float* xg = x + (size_t)n * C_ * HW_;
    float* og = out + (size_t)n * C_ * HW_;
    const unsigned short* wqf  = wqkf + (size_t)n * (K_ * C_);
    const unsigned short* vtfn = vtf  + (size_t)n * (K_ * C_);

    // ---- Hoisted invariant loads (fly concurrently with half-0 staging) ----
    const int mh = w;                                    // phase-3 c-quarter
    const int kt = w >> 1;                               // phase-1 kk-tile
    bf16x8 vf[8];
    #pragma unroll
    for (int mi = 0; mi < 8; ++mi)
        vf[mi] = *(const bf16x8*)(vtfn + ((size_t)(mh * 8 + mi) * 64 + l) * 8);
    bf16x8 b0 = *(const bf16x8*)(wqf + ((size_t)(0 * 2 + kt) * 64 + l) * 8);
    bf16x8 b1 = *(const bf16x8*)(wqf + ((size_t)(1 * 2 + kt) * 64 + l) * 8);

    const int px = t & 31, g = t >> 5;
    const float* xc = xg + p0 + px;
    const int pt = w & 1;
    f32x4 acc = {0.f, 0.f, 0.f, 0.f};
    const unsigned short* xbase = xl + lg * 256 + (pt * 16 + l15) * 8;

    // ---- Stage half 0 (cs 0-7): 32 loads in flight, cvtpk, write 16 KB ----
    {
        float r0[4][8];
        #pragma unroll
        for (int u = 0; u < 4; ++u)
            #pragma unroll
            for (int j = 0; j < 8; ++j)
                r0[u][j] = xc[(size_t)(g * 8 + u * 64 + j) * HW_];
        #pragma unroll
        for (int u = 0; u < 4; ++u) {
            const int cbase = g * 8 + u * 64;
            const int elem = (((cbase >> 5) & 7) * 1024) + (((cbase >> 3) & 3) * 256) + px * 8;
            i32x4 pk = { cvtpk(r0[u][0], r0[u][1]), cvtpk(r0[u][2], r0[u][3]),
                         cvtpk(r0[u][4], r0[u][5]), cvtpk(r0[u][6], r0[u][7]) };
            *(i32x4*)(xl + elem) = pk;
        }
    }
    __syncthreads();

    // ---- Issue half-1 loads; P1a (cs 0-7) runs underneath ----
    float r1[4][8];
    {
        #pragma unroll
        for (int u = 0; u < 4; ++u)
            #pragma unroll
            for (int j = 0; j < 8; ++j)
                r1[u][j] = xc[(size_t)(g * 8 + (u + 4) * 64 + j) * HW_];

        for (int cs = 0; cs < 8; ++cs) {
            bf16x8 b2 = *(const bf16x8*)(wqf + ((size_t)((cs + 2) * 2 + kt) * 64 + l) * 8);
            const bf16x8 af = *(const bf16x8*)(xbase + cs * 1024);
            acc = __builtin_amdgcn_mfma_f32_16x16x32_bf16(af, b0, acc, 0, 0, 0);
            b0 = b1; b1 = b2;
        }
    }
    __syncthreads();                       // all waves done reading half 0

    // ---- Overwrite buffer with half 1 (cs 8-15 remap to slots 0-7) ----
    {
        #pragma unroll
        for (int u = 0; u < 4; ++u) {
            const int cbase = g * 8 + (u + 4) * 64;
            const int elem = (((cbase >> 5) & 7) * 1024) + (((cbase >> 3) & 3) * 256) + px * 8;
            i32x4 pk = { cvtpk(r1[u][0], r1[u][1]), cvtpk(r1[u][2], r1[u][3]),
                         cvtpk(r1[u][4], r1[u][5]), cvtpk(r1[u][6], r1[u][7]) };
            *(i32x4*)(xl + elem) = pk;
        }
    }
    __syncthreads();

    // ---- P1b: cs 8-15 (remapped slots) ----
    {
        for (int cs = 8; cs < 16; ++cs) {
            bf16x8 b2;
            if (cs < 14) b2 = *(const bf16x8*)(wqf + ((size_t)((cs + 2) * 2 + kt) * 64 + l) * 8);
            const bf16x8 af = *(const bf16x8*)(xbase + (cs & 7) * 1024);
            acc = __builtin_amdgcn_mfma_f32_16x16x32_bf16(af, b0, acc, 0, 0, 0);
            b0 = b1; b1 = b2;
        }
        const float bq_ = bqk[n * K_ + kt * 16 + l15];
        #pragma unroll
        for (int r = 0; r < 4; ++r)
            e_lds[pt * 16 + lg * 4 + r][kt * 16 + l15] = acc[r] + bq_;
    }
    __syncthreads();

    // ---- Phase 2: per-lane softmax (float4 reads), cvt_pk pack ----
    bf16x8 paf0, paf1;
    {
        float e0[32], e1[32];
        #pragma unroll
        for (int i = 0; i < 8; ++i) {
            float4 q0 = *(const float4*)&e_lds[l15][4 * i];
            float4 q1 = *(const float4*)&e_lds[16 + l15][4 * i];
            e0[4*i] = q0.x; e0[4*i+1] = q0.y; e0[4*i+2] = q0.z; e0[4*i+3] = q0.w;
            e1[4*i] = q1.x; e1[4*i+1] = q1.y; e1[4*i+2] = q1.z; e1[4*i+3] = q1.w;
        }
        float m0 = e0[0], m1 = e1[0];
        #pragma unroll
        for (int k = 1; k < 32; ++k) { m0 = fmaxf(m0, e0[k]); m1 = fmaxf(m1, e1[k]); }
        float s0 = 0.f, s1 = 0.f;
        #pragma unroll
        for (int k = 0; k < 32; ++k) {
            e0[k] = __expf(e0[k] - m0); s0 += e0[k];
            e1[k] = __expf(e1[k] - m1); s1 += e1[k];
        }
        const float i0 = 1.f / s0, i1 = 1.f / s1;
        union { int i[4]; bf16x8 v; } u0, u1;
        #pragma unroll
        for (int jj = 0; jj < 4; ++jj) {
            u0.i[jj] = cvtpk(e0[8*lg + 2*jj] * i0, e0[8*lg + 2*jj + 1] * i0);
            u1.i[jj] = cvtpk(e1[8*lg + 2*jj] * i1, e1[8*lg + 2*jj + 1] * i1);
        }
        paf0 = u0.v; paf1 = u1.v;
    }

    // ---- Phase 3: PV MFMA from hoisted vf; residual from global fp32 (R13) ----
    {
        const float fs = scale[0];
        const int pxa = p0 + l15, pxb = p0 + 16 + l15;
        const int mt0 = mh * 8;

        float xr0[4], xr1[4];
        {
            const int c0 = mt0 * 16 + lg * 4;
            #pragma unroll
            for (int r = 0; r < 4; ++r) {
                xr0[r] = xg[(size_t)(c0 + r) * HW_ + pxa];
                xr1[r] = xg[(size_t)(c0 + r) * HW_ + pxb];
            }
        }
        for (int mi = 0; mi < 8; ++mi) {
            const int mt = mt0 + mi;
            float y0[4], y1[4];
            if (mi < 7) {
                const int cn = (mt + 1) * 16 + lg * 4;
                #pragma unroll
                for (int r = 0; r < 4; ++r) {
                    y0[r] = xg[(size_t)(cn + r) * HW_ + pxa];
                    y1[r] = xg[(size_t)(cn + r) * HW_ + pxb];
                }
            }
            f32x4 d0 = __builtin_amdgcn_mfma_f32_16x16x32_bf16(vf[mi], paf0, (f32x4){0.f,0.f,0.f,0.f}, 0, 0, 0);
            f32x4 d1 = __builtin_amdgcn_mfma_f32_16x16x32_bf16(vf[mi], paf1, (f32x4){0.f,0.f,0.f,0.f}, 0, 0, 0);
            const int cc = mt * 16 + lg * 4;
            #pragma unroll
            for (int r = 0; r < 4; ++r) {
                og[(size_t)(cc + r) * HW_ + pxa] = fs * d0[r] + xr0[r];
                og[(size_t)(cc + r) * HW_ + pxb] = fs * d1[r] + xr1[r];
            }
            #pragma unroll
            for (int r = 0; r < 4; ++r) { xr0[r] = y0[r]; xr1[r] = y1[r]; }
        }
    }
}

extern "C" void kernel_launch(void* const* d_in, const int* in_sizes, int n_in,
                              void* d_out, int out_size, void* d_ws, size_t ws_size,
                              hipStream_t stream) {
    const float* x     = (const float*)d_in[0];
    const float* y     = (const float*)d_in[1];
    const float* wq    = (const float*)d_in[2];
    const float* bq    = (const float*)d_in[3];
    const float* wk    = (const float*)d_in[4];
    const float* bk    = (const float*)d_in[5];
    const float* wv    = (const float*)d_in[6];
    const float* bv    = (const float*)d_in[7];
    const float* scale = (const float*)d_in[8];

    unsigned short* wqkf = (unsigned short*)d_ws;                       // 256 KB
    unsigned short* vtf  = wqkf + (size_t)N_ * K_ * C_;                 // 256 KB
    float* bqk = (float*)((char*)d_ws + 524288);                        // 1 KB

    prep_kernel<<<512, 256, 0, stream>>>(y, wq, bq, wk, bk, wv, bv, wqkf, bqk, vtf);
    main_kernel<<<1024, 256, 0, stream>>>(x, wqkf, vtf, bqk, scale, (float*)d_out);
}

// Round 25
// 54.660 us; speedup vs baseline: 1.2101x; 1.2101x over previous
//
#include <hip/hip_runtime.h>

// CPAMDec — R25 (final): byte-identical restore of R19, the measured optimum
// (54.7us total; main ~42us, VGPR 64). Split-barrier software pipeline
// (half-tile staging with 32 loads in flight; half1 loads issued under
// phase-1a MFMAs), v_cvt_pk_bf16_f32 packing, float4 softmax reads, hoisted
// vtf/b-frags, LDS bf16 residual, full-line writes, XCD swizzle.
//   energy[px][kk] = sum_c x_bf[px][c] * wqk_bf[c][kk] (+bqk)
//   out[c][px]     = fs * sum_kk vT_bf[c][kk] * attn_bf[kk][px] + x_bf[c][px]
// xl octet layout: elem(c,px) = (c>>5)*1024 + ((c>>3)&3)*256 + px*8 + (c&7)
// Frag layouts HW-verified R5/R6. ws: wqkf @0 | vtf @256K | bqk @512K

#define N_  8
#define C_  512
#define HW_ 4096
#define K_  32

typedef __attribute__((ext_vector_type(8))) short bf16x8;
typedef __attribute__((ext_vector_type(4))) float f32x4;
typedef __attribute__((ext_vector_type(4))) unsigned short u16x4;
typedef __attribute__((ext_vector_type(4))) int i32x4;

__device__ __forceinline__ unsigned short f2b(float f) {
    union { float f; unsigned u; } v; v.f = f;
    unsigned r = v.u + 0x7FFFu + ((v.u >> 16) & 1u);   // RNE
    return (unsigned short)(r >> 16);
}
__device__ __forceinline__ float b2f(unsigned short h) {
    union { unsigned u; float f; } v; v.u = ((unsigned)h) << 16; return v.f;
}
__device__ __forceinline__ int cvtpk(float a, float b) {   // bf16(a) | bf16(b)<<16, RNE
    int r;
    asm("v_cvt_pk_bf16_f32 %0, %1, %2" : "=v"(r) : "v"(a), "v"(b));
    return r;
}

// wqk frag slot: wqk[kk][c] -> elem ((cs*2+kt)*64 + g*16 + (kk&15))*8 + j
__device__ __forceinline__ int wqk_idx(int kk, int c) {
    return ((((c >> 5) * 2 + (kk >> 4)) * 64 + ((c >> 3) & 3) * 16 + (kk & 15)) << 3) + (c & 7);
}

__global__ __launch_bounds__(256) void prep_kernel(
    const float* __restrict__ y, const float* __restrict__ wq, const float* __restrict__ bq,
    const float* __restrict__ wk, const float* __restrict__ bk,
    const float* __restrict__ wv, const float* __restrict__ bv,
    unsigned short* __restrict__ wqkf, float* __restrict__ bqk, unsigned short* __restrict__ vtf)
{
    const int bid = blockIdx.x;
    const int t = threadIdx.x;

    if (bid < 256) {
        // role A: v rows -> vtf frags. block = (n, ct of 16 c).
        __shared__ float vred[3][4][16][8];              // 6 KB
        const int n   = bid >> 5;
        const int ct  = bid & 31;
        const int cl  = t & 15;
        const int kko = (t >> 4) & 3;
        const int jq4 = t >> 6;
        const int c   = ct * 16 + cl;

        const float* yb  = y  + ((size_t)n * K_ + kko * 8) * C_ + jq4 * 128;
        const float* wvb = wv + (size_t)c * C_ + jq4 * 128;
        float acc[8] = {0,0,0,0,0,0,0,0};
        #pragma unroll 4
        for (int jj = 0; jj < 32; ++jj) {
            float4 w4 = *(const float4*)(wvb + jj * 4);
            #pragma unroll
            for (int u = 0; u < 8; ++u) {
                float4 y4 = *(const float4*)(yb + (size_t)u * C_ + jj * 4);
                acc[u] += y4.x * w4.x + y4.y * w4.y + y4.z * w4.z + y4.w * w4.w;
            }
        }
        if (jq4 > 0) {
            #pragma unroll
            for (int u = 0; u < 8; ++u) vred[jq4 - 1][kko][cl][u] = acc[u];
        }
        __syncthreads();
        if (jq4 == 0) {
            const float bvc = bv[c];
            unsigned short o[8];
            #pragma unroll
            for (int u = 0; u < 8; ++u) {
                float s = acc[u] + vred[0][kko][cl][u] + vred[1][kko][cl][u]
                        + vred[2][kko][cl][u] + bvc;
                o[u] = f2b(s);
            }
            i32x4 pk = { (int)(o[0] | ((unsigned)o[1] << 16)), (int)(o[2] | ((unsigned)o[3] << 16)),
                         (int)(o[4] | ((unsigned)o[5] << 16)), (int)(o[6] | ((unsigned)o[7] << 16)) };
            *(i32x4*)(vtf + (size_t)n * (K_ * C_) + (size_t)((ct * 64 + kko * 16 + cl) * 8)) = pk;
        }
    } else {
        // role B: krow -> bqk, wqk frags. block = (n, kk)
        __shared__ __align__(16) float kp[2][128];
        __shared__ __align__(16) float kr[128];
        const int b = bid - 256;
        const int n = b >> 5, kk = b & 31;
        const int o = t & 127, half = t >> 7;

        const float* yb  = y  + ((size_t)n * K_ + kk) * C_ + half * 256;
        const float* wkb = wk + (size_t)o * C_ + half * 256;
        float a = 0.f;
        #pragma unroll 4
        for (int jq = 0; jq < 64; ++jq) {
            float4 w4 = *(const float4*)(wkb + jq * 4);
            float4 y4 = *(const float4*)(yb + jq * 4);
            a += y4.x * w4.x + y4.y * w4.y + y4.z * w4.z + y4.w * w4.w;
        }
        kp[half][o] = a;
        __syncthreads();
        if (t < 128) kr[t] = kp[0][t] + kp[1][t] + bk[t];
        __syncthreads();
        if (t < 64) {
            float s = kr[t] * bq[t] + kr[t + 64] * bq[t + 64];
            #pragma unroll
            for (int d = 32; d > 0; d >>= 1) s += __shfl_down(s, d);
            if (t == 0) bqk[n * K_ + kk] = s;
        }
        const int c1 = t, c2 = t + 256;
        float s1 = 0.f, s2 = 0.f;
        for (int oq = 0; oq < 32; ++oq) {
            float4 k4 = *(const float4*)(&kr[oq * 4]);
            const float* wq0 = wq + (size_t)(oq * 4) * C_;
            s1 += k4.x * wq0[c1] + k4.y * wq0[C_ + c1] + k4.z * wq0[2*C_ + c1] + k4.w * wq0[3*C_ + c1];
            s2 += k4.x * wq0[c2] + k4.y * wq0[C_ + c2] + k4.z * wq0[2*C_ + c2] + k4.w * wq0[3*C_ + c2];
        }
        unsigned short* wqf_n = wqkf + (size_t)n * (K_ * C_);
        wqf_n[wqk_idx(kk, c1)] = f2b(s1);
        wqf_n[wqk_idx(kk, c2)] = f2b(s2);
    }
}

__global__ __launch_bounds__(256) void main_kernel(
    const float* __restrict__ x, const unsigned short* __restrict__ wqkf,
    const unsigned short* __restrict__ vtf, const float* __restrict__ bqk,
    const float* __restrict__ scale, float* __restrict__ out)
{
    __shared__ __align__(16) unsigned short xl[16384];   // 32 KB, octet-contiguous
    __shared__ float e_lds[32][36];                       // 4.6 KB, 16B-aligned rows

    // XCD swizzle: 128 consecutive tiles (= one image n) per XCD
    const int bid = (blockIdx.x & 7) * 128 + (blockIdx.x >> 3);
    const int n  = bid >> 7;
    const int p0 = (bid & 127) * 32;
    const int t  = threadIdx.x;
    const int w  = t >> 6, l = t & 63;
    const int l15 = l & 15, lg = l >> 4;
    const float* xg = x + (size_t)n * C_ * HW_;
    float* og = out + (size_t)n * C_ * HW_;
    const unsigned short* wqf  = wqkf + (size_t)n * (K_ * C_);
    const unsigned short* vtfn = vtf  + (size_t)n * (K_ * C_);

    // ---- Hoisted invariant loads (fly concurrently with half-0 staging) ----
    const int mh = w;                                    // phase-3 c-quarter
    const int kt = w >> 1;                               // phase-1 kk-tile
    bf16x8 vf[8];
    #pragma unroll
    for (int mi = 0; mi < 8; ++mi)
        vf[mi] = *(const bf16x8*)(vtfn + ((size_t)(mh * 8 + mi) * 64 + l) * 8);
    bf16x8 b0 = *(const bf16x8*)(wqf + ((size_t)(0 * 2 + kt) * 64 + l) * 8);
    bf16x8 b1 = *(const bf16x8*)(wqf + ((size_t)(1 * 2 + kt) * 64 + l) * 8);

    const int px = t & 31, g = t >> 5;
    const float* xc = xg + p0 + px;
    const int pt = w & 1;
    f32x4 acc = {0.f, 0.f, 0.f, 0.f};
    const unsigned short* xbase = xl + lg * 256 + (pt * 16 + l15) * 8;

    // ---- Stage half 0 (octets 0-3 = cs 0-7): 32 loads in flight, then write ----
    {
        float r0[4][8];
        #pragma unroll
        for (int u = 0; u < 4; ++u)
            #pragma unroll
            for (int j = 0; j < 8; ++j)
                r0[u][j] = xc[(size_t)(g * 8 + u * 64 + j) * HW_];
        #pragma unroll
        for (int u = 0; u < 4; ++u) {
            const int cbase = g * 8 + u * 64;
            const int elem = ((cbase >> 5) * 1024) + (((cbase >> 3) & 3) * 256) + px * 8;
            i32x4 pk = { cvtpk(r0[u][0], r0[u][1]), cvtpk(r0[u][2], r0[u][3]),
                         cvtpk(r0[u][4], r0[u][5]), cvtpk(r0[u][6], r0[u][7]) };
            *(i32x4*)(xl + elem) = pk;
        }
    }
    __syncthreads();

    // ---- Issue half-1 loads; phase-1a MFMAs (cs 0-7) run underneath; write half 1 ----
    {
        float r1[4][8];
        #pragma unroll
        for (int u = 0; u < 4; ++u)
            #pragma unroll
            for (int j = 0; j < 8; ++j)
                r1[u][j] = xc[(size_t)(g * 8 + (u + 4) * 64 + j) * HW_];

        for (int cs = 0; cs < 8; ++cs) {
            bf16x8 b2 = *(const bf16x8*)(wqf + ((size_t)((cs + 2) * 2 + kt) * 64 + l) * 8);
            const bf16x8 af = *(const bf16x8*)(xbase + cs * 1024);
            acc = __builtin_amdgcn_mfma_f32_16x16x32_bf16(af, b0, acc, 0, 0, 0);
            b0 = b1; b1 = b2;
        }

        #pragma unroll
        for (int u = 0; u < 4; ++u) {
            const int cbase = g * 8 + (u + 4) * 64;
            const int elem = ((cbase >> 5) * 1024) + (((cbase >> 3) & 3) * 256) + px * 8;
            i32x4 pk = { cvtpk(r1[u][0], r1[u][1]), cvtpk(r1[u][2], r1[u][3]),
                         cvtpk(r1[u][4], r1[u][5]), cvtpk(r1[u][6], r1[u][7]) };
            *(i32x4*)(xl + elem) = pk;
        }
    }
    __syncthreads();

    // ---- Phase 1b: cs 8-15 ----
    {
        for (int cs = 8; cs < 16; ++cs) {
            bf16x8 b2;
            if (cs < 14) b2 = *(const bf16x8*)(wqf + ((size_t)((cs + 2) * 2 + kt) * 64 + l) * 8);
            const bf16x8 af = *(const bf16x8*)(xbase + cs * 1024);
            acc = __builtin_amdgcn_mfma_f32_16x16x32_bf16(af, b0, acc, 0, 0, 0);
            b0 = b1; b1 = b2;
        }
        const float bq_ = bqk[n * K_ + kt * 16 + l15];
        #pragma unroll
        for (int r = 0; r < 4; ++r)
            e_lds[pt * 16 + lg * 4 + r][kt * 16 + l15] = acc[r] + bq_;
    }
    __syncthreads();

    // ---- Phase 2: per-lane softmax (float4 reads), cvt_pk pack ----
    bf16x8 paf0, paf1;
    {
        float e0[32], e1[32];
        #pragma unroll
        for (int i = 0; i < 8; ++i) {
            float4 q0 = *(const float4*)&e_lds[l15][4 * i];
            float4 q1 = *(const float4*)&e_lds[16 + l15][4 * i];
            e0[4*i] = q0.x; e0[4*i+1] = q0.y; e0[4*i+2] = q0.z; e0[4*i+3] = q0.w;
            e1[4*i] = q1.x; e1[4*i+1] = q1.y; e1[4*i+2] = q1.z; e1[4*i+3] = q1.w;
        }
        float m0 = e0[0], m1 = e1[0];
        #pragma unroll
        for (int k = 1; k < 32; ++k) { m0 = fmaxf(m0, e0[k]); m1 = fmaxf(m1, e1[k]); }
        float s0 = 0.f, s1 = 0.f;
        #pragma unroll
        for (int k = 0; k < 32; ++k) {
            e0[k] = __expf(e0[k] - m0); s0 += e0[k];
            e1[k] = __expf(e1[k] - m1); s1 += e1[k];
        }
        const float i0 = 1.f / s0, i1 = 1.f / s1;
        union { int i[4]; bf16x8 v; } u0, u1;
        #pragma unroll
        for (int jj = 0; jj < 4; ++jj) {
            u0.i[jj] = cvtpk(e0[8*lg + 2*jj] * i0, e0[8*lg + 2*jj + 1] * i0);
            u1.i[jj] = cvtpk(e1[8*lg + 2*jj] * i1, e1[8*lg + 2*jj + 1] * i1);
        }
        paf0 = u0.v; paf1 = u1.v;
    }

    // ---- Phase 3: PV MFMA from hoisted vf; residual = 2 ds_read_b64/mi ----
    {
        const float fs = scale[0];
        const int pxa = p0 + l15, pxb = p0 + 16 + l15;
        const int mt0 = mh * 8;

        #pragma unroll
        for (int mi = 0; mi < 8; ++mi) {
            const int mt = mt0 + mi;
            f32x4 d0 = __builtin_amdgcn_mfma_f32_16x16x32_bf16(vf[mi], paf0, (f32x4){0.f,0.f,0.f,0.f}, 0, 0, 0);
            f32x4 d1 = __builtin_amdgcn_mfma_f32_16x16x32_bf16(vf[mi], paf1, (f32x4){0.f,0.f,0.f,0.f}, 0, 0, 0);
            const int base = (mt >> 1) * 1024 + ((2 * mt + (lg >> 1)) & 3) * 256 + (lg & 1) * 4;
            const u16x4 ra = *(const u16x4*)(xl + base + l15 * 8);
            const u16x4 rb = *(const u16x4*)(xl + base + (16 + l15) * 8);
            const int cc = mt * 16 + lg * 4;
            #pragma unroll
            for (int r = 0; r < 4; ++r) {
                og[(size_t)(cc + r) * HW_ + pxa] = fs * d0[r] + b2f(ra[r]);
                og[(size_t)(cc + r) * HW_ + pxb] = fs * d1[r] + b2f(rb[r]);
            }
        }
    }
}

extern "C" void kernel_launch(void* const* d_in, const int* in_sizes, int n_in,
                              void* d_out, int out_size, void* d_ws, size_t ws_size,
                              hipStream_t stream) {
    const float* x     = (const float*)d_in[0];
    const float* y     = (const float*)d_in[1];
    const float* wq    = (const float*)d_in[2];
    const float* bq    = (const float*)d_in[3];
    const float* wk    = (const float*)d_in[4];
    const float* bk    = (const float*)d_in[5];
    const float* wv    = (const float*)d_in[6];
    const float* bv    = (const float*)d_in[7];
    const float* scale = (const float*)d_in[8];

    unsigned short* wqkf = (unsigned short*)d_ws;                       // 256 KB
    unsigned short* vtf  = wqkf + (size_t)N_ * K_ * C_;                 // 256 KB
    float* bqk = (float*)((char*)d_ws + 524288);                        // 1 KB

    prep_kernel<<<512, 256, 0, stream>>>(y, wq, bq, wk, bk, wv, bv, wqkf, bqk, vtf);
    main_kernel<<<1024, 256, 0, stream>>>(x, wqkf, vtf, bqk, scale, (float*)d_out);
}